// Round 9
// baseline (511.719 us; speedup 1.0000x reference)
//
#include <hip/hip_runtime.h>
#include <hip/hip_bf16.h>

#define FDIM 256
#define FOUT 40
#define RPB 256   // rows per bucket in CSR-build binning
#define ROWB 80   // bytes per bf16 table row (40 * 2)

typedef __attribute__((ext_vector_type(8))) short short8;
typedef __attribute__((ext_vector_type(4))) float floatx4;

__device__ __forceinline__ float bf2f(unsigned short u) {
  unsigned int x = ((unsigned int)u) << 16;
  float f;
  __builtin_memcpy(&f, &x, 4);
  return f;
}
__device__ __forceinline__ unsigned short f2bf(float f) {
  __hip_bfloat16 h = __float2bfloat16(f);
  unsigned short u;
  __builtin_memcpy(&u, &h, 2);
  return u;
}
// packed-bf16 dword helpers
__device__ __forceinline__ float blo(unsigned int v) {
  unsigned int x = v << 16; float f; __builtin_memcpy(&f, &x, 4); return f;
}
__device__ __forceinline__ float bhi(unsigned int v) {
  unsigned int x = v & 0xFFFF0000u; float f; __builtin_memcpy(&f, &x, 4); return f;
}

// ---------------- edge_index layout detection ----------------

__global__ void detect_k(const int* __restrict__ raw, int nwords, int* __restrict__ flag) {
  if (threadIdx.x == 0) *flag = 0;
  __syncthreads();
  int found = 0;
  for (int w = 1 + 2 * threadIdx.x; w < nwords; w += 512)
    if (raw[w] != 0) { found = 1; break; }
  if (found) atomicOr(flag, 1);  // 1 => int32 layout
}

// legacy normalization (fallback path only)
__global__ void normalize_k(const int* __restrict__ raw, const int* __restrict__ flag,
                            int* __restrict__ srcN, int* __restrict__ dstN, int e) {
  int i = blockIdx.x * 256 + threadIdx.x;
  if (i >= e) return;
  if (*flag) {
    srcN[i] = raw[i];
    dstN[i] = raw[e + i];
  } else {
    srcN[i] = raw[2 * i];
    dstN[i] = raw[2 * (e + i)];
  }
}

// ---------------- legacy CSR build (fallback for N > 2^17) ----------------

__global__ void zero_cnt_k(int* cnt, int n) {
  int i = blockIdx.x * 256 + threadIdx.x;
  if (i < n) cnt[i] = 0;
}

__global__ void count_k(const int* __restrict__ dst, int* __restrict__ cnt, int e, int n) {
  int i = blockIdx.x * 256 + threadIdx.x;
  if (i < e) {
    int d = dst[i];
    if (d >= 0 && d < n) atomicAdd(&cnt[d], 1);
  }
}

__global__ void dis_leg_k(const int* __restrict__ cnt, float* __restrict__ dis, int n) {
  int i = blockIdx.x * 256 + threadIdx.x;
  if (i < n) dis[i] = rsqrtf((float)cnt[i] + 1.0f);
}

__global__ void scan_a_k(const int* __restrict__ cnt, int* __restrict__ excl,
                         int* __restrict__ bsum, int n) {
  __shared__ int sh[1024];
  int t = threadIdx.x;
  int gid = blockIdx.x * 1024 + t;
  int v = (gid < n) ? cnt[gid] : 0;
  sh[t] = v;
  __syncthreads();
  for (int off = 1; off < 1024; off <<= 1) {
    int x = (t >= off) ? sh[t - off] : 0;
    __syncthreads();
    sh[t] += x;
    __syncthreads();
  }
  if (gid < n) excl[gid] = sh[t] - v;
  if (t == 1023) bsum[blockIdx.x] = sh[1023];
}

__global__ void scan_b_k(int* __restrict__ bsum, int nb) {
  __shared__ int sh[1024];
  int t = threadIdx.x;
  int v = (t < nb) ? bsum[t] : 0;
  sh[t] = v;
  __syncthreads();
  for (int off = 1; off < 1024; off <<= 1) {
    int x = (t >= off) ? sh[t - off] : 0;
    __syncthreads();
    sh[t] += x;
    __syncthreads();
  }
  if (t < nb) bsum[t] = sh[t] - v;
}

__global__ void scan_c_k(int* __restrict__ row_ptr, const int* __restrict__ bsum,
                         const int* __restrict__ cnt, int* __restrict__ cursor, int n) {
  int gid = blockIdx.x * 1024 + threadIdx.x;
  if (gid < n) {
    int r = row_ptr[gid] + bsum[blockIdx.x];
    row_ptr[gid] = r;
    cursor[gid] = r;
    if (gid == n - 1) row_ptr[n] = r + cnt[gid];
  }
}

__global__ void fill_k(const int* __restrict__ src, const int* __restrict__ dst,
                       int* __restrict__ cursor, int* __restrict__ col, int e, int n) {
  int i = blockIdx.x * 256 + threadIdx.x;
  if (i < e) {
    int d = dst[i];
    if (d >= 0 && d < n) {
      int slot = atomicAdd(&cursor[d], 1);
      int s = src[i];
      s = min(max(s, 0), n - 1);
      col[slot] = s * ROWB;  // byte offset into table
    }
  }
}

// ---------------- bucket-first CSR build (no global per-row atomics) ----------------
// bucket = dst >> 8 (256 rows, <= 512 buckets for N <= 2^17)

__global__ __launch_bounds__(512) void zerob_k(int* __restrict__ bcnt, int nbuck) {
  int t = threadIdx.x;
  if (t < nbuck) bcnt[t] = 0;
}

// pass 0: bucket histogram straight from raw edges; <=512 global atomics per block
__global__ __launch_bounds__(256) void bhist_k(
    const int* __restrict__ raw, const int* __restrict__ flag,
    int* __restrict__ bcnt, int e, int n, int nbuck, int cpb) {
  __shared__ int hist[512];
  int t = threadIdx.x;
  for (int b = t; b < nbuck; b += 256) hist[b] = 0;
  __syncthreads();
  int fl = *flag;
  int start = blockIdx.x * cpb;
  int endc = min(e, start + cpb);
  for (int i = start + t; i < endc; i += 256) {
    int d = fl ? raw[e + i] : raw[2 * (e + i)];
    if (d >= 0 && d < n) atomicAdd(&hist[d >> 8], 1);
  }
  __syncthreads();
  for (int b = t; b < nbuck; b += 256)
    if (hist[b]) atomicAdd(&bcnt[b], hist[b]);
}

// pass 1: scan bucket counts -> bases + cursors (single block)
__global__ __launch_bounds__(512) void bscan_k(
    const int* __restrict__ bcnt, int* __restrict__ bbase,
    int* __restrict__ bcur, int nbuck) {
  __shared__ int sh[512];
  int t = threadIdx.x;
  int v = (t < nbuck) ? bcnt[t] : 0;
  sh[t] = v;
  __syncthreads();
  for (int off = 1; off < 512; off <<= 1) {
    int x = (t >= off) ? sh[t - off] : 0;
    __syncthreads();
    sh[t] += x;
    __syncthreads();
  }
  if (t < nbuck) {
    int ex = sh[t] - v;
    bbase[t] = ex;
    bcur[t] = ex;
  }
  if (t == nbuck - 1) bbase[nbuck] = sh[t];
}

// pass 2: bin edges (from raw) into per-bucket contiguous regions; payload (dst&255, src)
__global__ __launch_bounds__(1024) void bin2_k(
    const int* __restrict__ raw, const int* __restrict__ flag,
    int* __restrict__ bcur, unsigned int* __restrict__ binned,
    int e, int n, int nbuck, int cpb) {
  __shared__ int hist[512];
  __shared__ int base_[512];
  __shared__ int cnt2[512];
  int t = threadIdx.x;
  int fl = *flag;
  int start = blockIdx.x * cpb;
  int endc = min(e, start + cpb);
  for (int b = t; b < nbuck; b += 1024) { hist[b] = 0; cnt2[b] = 0; }
  __syncthreads();
  for (int i = start + t; i < endc; i += 1024) {
    int d = fl ? raw[e + i] : raw[2 * (e + i)];
    if (d >= 0 && d < n) atomicAdd(&hist[d >> 8], 1);
  }
  __syncthreads();
  for (int b = t; b < nbuck; b += 1024) {
    int h = hist[b];
    base_[b] = h ? atomicAdd(&bcur[b], h) : 0;
  }
  __syncthreads();
  for (int i = start + t; i < endc; i += 1024) {
    int d = fl ? raw[e + i] : raw[2 * (e + i)];
    if (d >= 0 && d < n) {
      int s = fl ? raw[i] : raw[2 * i];
      s = min(max(s, 0), n - 1);
      int bk = d >> 8;
      int pos = base_[bk] + atomicAdd(&cnt2[bk], 1);
      binned[pos] = (((unsigned int)(d & 255)) << 17) | (unsigned int)s;
    }
  }
}

// pass 3: per-bucket row count + dis + row_ptr (LDS scan) + scatter to col (byte offsets)
__global__ __launch_bounds__(256) void scatcnt_k(
    const unsigned int* __restrict__ binned, const int* __restrict__ bbase,
    int* __restrict__ row_ptr, float* __restrict__ dis,
    int* __restrict__ col, int n) {
  __shared__ int cnt[RPB];
  __shared__ int sc[RPB];
  __shared__ int cur[RPB];
  int b = blockIdx.x;
  int r0 = b * RPB;
  int r1 = min(n, r0 + RPB);
  int nr = r1 - r0;
  int t = threadIdx.x;
  cnt[t] = 0;
  __syncthreads();
  int e0 = bbase[b], e1 = bbase[b + 1];
  for (int i = e0 + t; i < e1; i += 256)
    atomicAdd(&cnt[binned[i] >> 17], 1);
  __syncthreads();
  int v = cnt[t];
  if (t < nr) dis[r0 + t] = rsqrtf((float)v + 1.0f);
  sc[t] = v;
  __syncthreads();
  for (int off = 1; off < 256; off <<= 1) {
    int x = (t >= off) ? sc[t - off] : 0;
    __syncthreads();
    sc[t] += x;
    __syncthreads();
  }
  int base = e0 + sc[t] - v;  // exclusive
  cur[t] = base;
  if (t < nr) row_ptr[r0 + t] = base;
  if (t == 0 && r1 == n) row_ptr[n] = e1;
  __syncthreads();
  for (int i = e0 + t; i < e1; i += 256) {
    unsigned int p = binned[i];
    int dlow = (int)(p >> 17);
    int slot = atomicAdd(&cur[dlow], 1);
    col[slot] = (int)(p & 0x1FFFF) * ROWB;  // byte offset
  }
}

// ---------------- weight precomputation (linear collapse) ----------------

__global__ __launch_bounds__(64) void wc_k(const float* __restrict__ W2,
                                           const float* __restrict__ Wlin,
                                           float* __restrict__ Wc) {
  __shared__ float row[FDIM];
  int k = blockIdx.x, t = threadIdx.x;
  for (int j = t; j < FDIM; j += 64) row[j] = W2[(size_t)k * FDIM + j];
  __syncthreads();
  if (t < FOUT) {
    float acc = 0.f;
    for (int j = 0; j < FDIM; ++j) acc += row[j] * Wlin[(size_t)j * FOUT + t];
    Wc[(size_t)k * FOUT + t] = acc;
  }
}

__global__ __launch_bounds__(64) void wfull_k(const float* __restrict__ W1,
                                              const float* __restrict__ Wc,
                                              float* __restrict__ Wfull) {
  __shared__ float row[FDIM];
  int k = blockIdx.x, t = threadIdx.x;
  for (int j = t; j < FDIM; j += 64) row[j] = W1[(size_t)k * FDIM + j];
  __syncthreads();
  if (t < FOUT) {
    float acc = 0.f;
    for (int j = 0; j < FDIM; ++j) acc += row[j] * Wc[(size_t)j * FOUT + t];
    Wfull[(size_t)k * FOUT + t] = acc;
  }
}

__global__ __launch_bounds__(64) void rvec_k(const float* __restrict__ b1,
                                             const float* __restrict__ Wc,
                                             const float* __restrict__ b2,
                                             const float* __restrict__ Wlin,
                                             const float* __restrict__ blin,
                                             float* __restrict__ b1c,
                                             float* __restrict__ r2) {
  int t = threadIdx.x;
  if (t < FOUT) {
    float a = 0.f, b = blin[t];
    for (int j = 0; j < FDIM; ++j) {
      a += b1[j] * Wc[(size_t)j * FOUT + t];
      b += b2[j] * Wlin[(size_t)j * FOUT + t];
    }
    b1c[t] = a;
    r2[t] = b;
  }
}

// WfT: bf16 B^T for MFMA, 48 rows (40 real + 8 zero-pad) x 256
__global__ void wft_k(const float* __restrict__ Wfull, unsigned short* __restrict__ WfT) {
  int o = blockIdx.x, k = threadIdx.x;
  WfT[(size_t)o * FDIM + k] = (o < FOUT) ? f2bf(Wfull[(size_t)k * FOUT + o]) : (unsigned short)0;
}

// ---------------- proj: Ys[N][40] = bf16( (X @ Wfull) * dis_row ), dword-packed out ----------------

__global__ __launch_bounds__(256) void proj_k(
    const float* __restrict__ X, const unsigned short* __restrict__ WfT,
    const float* __restrict__ dis, unsigned int* __restrict__ Ys32, int M) {
  __shared__ __align__(16) unsigned short Asm[64 * 40];   // staging + epilogue repack
  __shared__ __align__(16) unsigned short Bsm[48 * 264];
  int t = threadIdx.x;
  int block_m = blockIdx.x * 64;
  int lane = t & 63, wave = t >> 6;
  int q = lane >> 4, rcol = lane & 15;
  for (int idx = t; idx < 48 * 256; idx += 256) {
    int o = idx >> 8, k = idx & 255;
    Bsm[o * 264 + k] = WfT[(size_t)o * FDIM + k];
  }
  floatx4 acc[3] = {};
  int arow = t >> 2, cc = (t & 3) * 8;
  int gm = block_m + arow;
  for (int kk = 0; kk < FDIM; kk += 32) {
    __syncthreads();  // also protects Bsm staging on first iteration
    {
      float4 v0 = {0, 0, 0, 0}, v1 = {0, 0, 0, 0};
      if (gm < M) {
        v0 = *(const float4*)(X + (size_t)gm * FDIM + kk + cc);
        v1 = *(const float4*)(X + (size_t)gm * FDIM + kk + cc + 4);
      }
      short8 pk;
      pk[0] = (short)f2bf(v0.x); pk[1] = (short)f2bf(v0.y);
      pk[2] = (short)f2bf(v0.z); pk[3] = (short)f2bf(v0.w);
      pk[4] = (short)f2bf(v1.x); pk[5] = (short)f2bf(v1.y);
      pk[6] = (short)f2bf(v1.z); pk[7] = (short)f2bf(v1.w);
      *(short8*)(Asm + arow * 40 + cc) = pk;
    }
    __syncthreads();
    short8 af = *(const short8*)(Asm + (wave * 16 + rcol) * 40 + q * 8);
    short8 b0 = *(const short8*)(Bsm + (rcol)*264 + kk + q * 8);
    short8 b1f = *(const short8*)(Bsm + (16 + rcol) * 264 + kk + q * 8);
    short8 b2f = *(const short8*)(Bsm + (32 + rcol) * 264 + kk + q * 8);
    acc[0] = __builtin_amdgcn_mfma_f32_16x16x32_bf16(af, b0, acc[0], 0, 0, 0);
    acc[1] = __builtin_amdgcn_mfma_f32_16x16x32_bf16(af, b1f, acc[1], 0, 0, 0);
    acc[2] = __builtin_amdgcn_mfma_f32_16x16x32_bf16(af, b2f, acc[2], 0, 0, 0);
  }
  // epilogue: scale + bf16 into LDS rows, then coalesced dword copy-out
  __syncthreads();
#pragma unroll
  for (int rr = 0; rr < 4; ++rr) {
    int ml = wave * 16 + q * 4 + rr;
    int m = block_m + ml;
    float sc = (m < M) ? dis[m] : 0.f;
    unsigned short* lrow = Asm + ml * 40;
    lrow[rcol] = f2bf(acc[0][rr] * sc);
    lrow[16 + rcol] = f2bf(acc[1][rr] * sc);
    if (rcol < 8) lrow[32 + rcol] = f2bf(acc[2][rr] * sc);
  }
  __syncthreads();
  const unsigned int* A32 = (const unsigned int*)Asm;
  for (int idx = t; idx < 64 * 20; idx += 256) {
    int r = idx / 20, c = idx - r * 20;
    int m = block_m + r;
    if (m < M) Ys32[(size_t)m * 20 + c] = A32[idx];
  }
}

// ---------------- agg kernels: 6 edges/step, 10 lanes/edge, dwordx2 (8B) loads ----
// lane -> group e = lane/10, fp2 = lane%10. col[] holds pre-scaled byte offsets.
// Full-row guarded issue: all ceil(cc/6) <= 11 bpermute+load pairs issued up
// front under wave-uniform guards (cc is row-level) -> MLP = ceil(deg/6), no
// serial tail. 10 requests/edge at the proven 8B sweet spot.

__global__ __launch_bounds__(256) void agg1_k(
    const unsigned int* __restrict__ T32, const int* __restrict__ row_ptr,
    const int* __restrict__ col, const float* __restrict__ dis,
    const float* __restrict__ b1c, unsigned int* __restrict__ O32, int n) {
  int wave = threadIdx.x >> 6, lane = threadIdx.x & 63;
  int wid = blockIdx.x * 4 + wave;
  int nw = gridDim.x * 4;
  int e = lane / 10;
  int fp2 = lane - e * 10;
  if (e > 5) { e = 5; fp2 = 0; }  // lanes 60-63 duplicate group 5 lane 0
  int e4 = e * 4;
  bool g0 = (e == 0);
  float4 bv = *(const float4*)(b1c + 4 * fp2);
  const char* Tb = (const char*)T32 + fp2 * 8;
  for (int i = wid; i < n; i += nw) {
    uint2 sv = *(const uint2*)(Tb + (size_t)i * ROWB);
    float a0 = g0 ? blo(sv.x) : 0.f;
    float a1 = g0 ? bhi(sv.x) : 0.f;
    float a2 = g0 ? blo(sv.y) : 0.f;
    float a3 = g0 ? bhi(sv.y) : 0.f;
    int beg = row_ptr[i], end = row_ptr[i + 1];
    for (int j0 = beg; j0 < end; j0 += 64) {
      int jj = j0 + lane;
      int cs = (jj < end) ? col[jj] : 0;  // byte offsets
      int cc = min(64, end - j0);
      uint2 g[11];
#pragma unroll
      for (int u = 0; u < 11; ++u) {
        int kb = u * 6;
        if (kb < cc) {  // wave-uniform guard
          int off = __builtin_amdgcn_ds_bpermute(kb * 4 + e4, cs);
          g[u] = *(const uint2*)(Tb + (unsigned int)off);
        }
      }
#pragma unroll
      for (int u = 0; u < 11; ++u) {
        int kb = u * 6;
        if (kb + 6 <= cc) {  // full step, unpredicated
          a0 += blo(g[u].x); a1 += bhi(g[u].x);
          a2 += blo(g[u].y); a3 += bhi(g[u].y);
        } else if (kb < cc) {  // partial step, weight-predicated
          float wgt = (kb + e < cc) ? 1.f : 0.f;
          a0 = fmaf(wgt, blo(g[u].x), a0);
          a1 = fmaf(wgt, bhi(g[u].x), a1);
          a2 = fmaf(wgt, blo(g[u].y), a2);
          a3 = fmaf(wgt, bhi(g[u].y), a3);
        }
      }
    }
    // reduce across 6 groups (stride 10)
    a0 += __shfl(a0, lane + 30); a1 += __shfl(a1, lane + 30);
    a2 += __shfl(a2, lane + 30); a3 += __shfl(a3, lane + 30);
    a0 += __shfl(a0, lane + 10) + __shfl(a0, lane + 20);
    a1 += __shfl(a1, lane + 10) + __shfl(a1, lane + 20);
    a2 += __shfl(a2, lane + 10) + __shfl(a2, lane + 20);
    a3 += __shfl(a3, lane + 10) + __shfl(a3, lane + 20);
    if (g0) {
      float di = dis[i];
      uint2 p;
      p.x = (unsigned int)f2bf((di * a0 + bv.x) * di) |
            ((unsigned int)f2bf((di * a1 + bv.y) * di) << 16);
      p.y = (unsigned int)f2bf((di * a2 + bv.z) * di) |
            ((unsigned int)f2bf((di * a3 + bv.w) * di) << 16);
      *(uint2*)((char*)O32 + (size_t)i * ROWB + fp2 * 8) = p;
    }
  }
}

__global__ __launch_bounds__(256) void agg2_k(
    const unsigned int* __restrict__ T32, const int* __restrict__ row_ptr,
    const int* __restrict__ col, const float* __restrict__ dis,
    const float* __restrict__ r2, float* __restrict__ out, int n) {
  int wave = threadIdx.x >> 6, lane = threadIdx.x & 63;
  int wid = blockIdx.x * 4 + wave;
  int nw = gridDim.x * 4;
  int e = lane / 10;
  int fp2 = lane - e * 10;
  if (e > 5) { e = 5; fp2 = 0; }
  int e4 = e * 4;
  bool g0 = (e == 0);
  float4 rv = *(const float4*)(r2 + 4 * fp2);
  const char* Tb = (const char*)T32 + fp2 * 8;
  for (int i = wid; i < n; i += nw) {
    uint2 sv = *(const uint2*)(Tb + (size_t)i * ROWB);
    float a0 = g0 ? blo(sv.x) : 0.f;
    float a1 = g0 ? bhi(sv.x) : 0.f;
    float a2 = g0 ? blo(sv.y) : 0.f;
    float a3 = g0 ? bhi(sv.y) : 0.f;
    int beg = row_ptr[i], end = row_ptr[i + 1];
    for (int j0 = beg; j0 < end; j0 += 64) {
      int jj = j0 + lane;
      int cs = (jj < end) ? col[jj] : 0;
      int cc = min(64, end - j0);
      uint2 g[11];
#pragma unroll
      for (int u = 0; u < 11; ++u) {
        int kb = u * 6;
        if (kb < cc) {
          int off = __builtin_amdgcn_ds_bpermute(kb * 4 + e4, cs);
          g[u] = *(const uint2*)(Tb + (unsigned int)off);
        }
      }
#pragma unroll
      for (int u = 0; u < 11; ++u) {
        int kb = u * 6;
        if (kb + 6 <= cc) {
          a0 += blo(g[u].x); a1 += bhi(g[u].x);
          a2 += blo(g[u].y); a3 += bhi(g[u].y);
        } else if (kb < cc) {
          float wgt = (kb + e < cc) ? 1.f : 0.f;
          a0 = fmaf(wgt, blo(g[u].x), a0);
          a1 = fmaf(wgt, bhi(g[u].x), a1);
          a2 = fmaf(wgt, blo(g[u].y), a2);
          a3 = fmaf(wgt, bhi(g[u].y), a3);
        }
      }
    }
    a0 += __shfl(a0, lane + 30); a1 += __shfl(a1, lane + 30);
    a2 += __shfl(a2, lane + 30); a3 += __shfl(a3, lane + 30);
    a0 += __shfl(a0, lane + 10) + __shfl(a0, lane + 20);
    a1 += __shfl(a1, lane + 10) + __shfl(a1, lane + 20);
    a2 += __shfl(a2, lane + 10) + __shfl(a2, lane + 20);
    a3 += __shfl(a3, lane + 10) + __shfl(a3, lane + 20);
    float di = dis[i];
    float v0 = g0 ? (di * a0 + rv.x) : -3.4e38f;
    float v1 = g0 ? (di * a1 + rv.y) : -3.4e38f;
    float v2 = g0 ? (di * a2 + rv.z) : -3.4e38f;
    float v3 = g0 ? (di * a3 + rv.w) : -3.4e38f;
    float m = fmaxf(fmaxf(v0, v1), fmaxf(v2, v3));
#pragma unroll
    for (int off = 32; off; off >>= 1) m = fmaxf(m, __shfl_xor(m, off));
    float s = g0 ? (__expf(v0 - m) + __expf(v1 - m) + __expf(v2 - m) + __expf(v3 - m)) : 0.f;
#pragma unroll
    for (int off = 32; off; off >>= 1) s += __shfl_xor(s, off);
    float lg = m + __logf(s);
    if (g0) {
      float4 o = {v0 - lg, v1 - lg, v2 - lg, v3 - lg};
      *(float4*)(out + (size_t)i * FOUT + 4 * fp2) = o;
    }
  }
}

// ---------------- launch ----------------

extern "C" void kernel_launch(void* const* d_in, const int* in_sizes, int n_in,
                              void* d_out, int out_size, void* d_ws, size_t ws_size,
                              hipStream_t stream) {
  const float* x   = (const float*)d_in[0];
  const int* eraw  = (const int*)d_in[1];
  const float* W1  = (const float*)d_in[2];
  const float* b1  = (const float*)d_in[3];
  const float* W2  = (const float*)d_in[4];
  const float* b2  = (const float*)d_in[5];
  const float* Wl  = (const float*)d_in[6];
  const float* bl  = (const float*)d_in[7];
  float* out = (float*)d_out;

  const int N = in_sizes[0] / FDIM;
  const int E = in_sizes[1] / 2;

  char* w = (char*)d_ws;
  size_t off = 0;
  auto take = [&](size_t bytes) {
    void* p = w + off;
    off = (off + bytes + 255) & ~(size_t)255;
    return p;
  };
  int* cnt     = (int*)take((size_t)N * 4);   // legacy path only
  int* cursor  = (int*)take((size_t)N * 4);   // legacy path only
  int* row_ptr = (int*)take((size_t)(N + 1) * 4);
  float* dis   = (float*)take((size_t)N * 4);
  int* bsum    = (int*)take(4096);
  int* eflag   = (int*)take(256);
  int* bcnt    = (int*)take(512 * 4);
  int* bbase   = (int*)take(513 * 4);
  int* bcur    = (int*)take(512 * 4);
  float* Wc    = (float*)take((size_t)FDIM * FOUT * 4);
  float* Wfull = (float*)take((size_t)FDIM * FOUT * 4);
  unsigned short* WfT = (unsigned short*)take((size_t)48 * FDIM * 2);
  float* b1c   = (float*)take(256);
  float* r2    = (float*)take(256);
  int* colx    = (int*)take((size_t)E * 4);

  size_t pairBytes = (size_t)2 * E * 4;
  size_t tabBytes  = (size_t)N * FOUT * 2;  // bf16 tables (20 dwords/row)
  size_t rABytes = pairBytes > tabBytes ? pairBytes : tabBytes;
  char* regionA = (char*)take(rABytes);
  int* srcN = (int*)regionA;
  int* dstN = srcN + E;
  unsigned int* Ys32 = (unsigned int*)regionA;
  size_t binBytes = (size_t)E * 4;
  size_t rBBytes = binBytes > tabBytes ? binBytes : tabBytes;
  char* regionB = (char*)take(rBBytes);
  unsigned int* binned = (unsigned int*)regionB;
  unsigned int* Z1s32 = (unsigned int*)regionB;
  (void)n_in; (void)out_size; (void)ws_size;

  int gE = (E + 255) / 256;
  int gN = (N + 255) / 256;
  int NB = (N + 1023) / 1024;
  int gP = (N + 63) / 64;
  int nbuck = (N + RPB - 1) / RPB;
  bool bucketed = (N <= (1 << 17));

  int probe_words = 65536 < 2 * E ? 65536 : 2 * E;
  hipLaunchKernelGGL(detect_k, dim3(1), dim3(256), 0, stream, eraw, probe_words, eflag);

  if (bucketed) {
    int nblk = 256;
    int cpb = (E + nblk - 1) / nblk;
    hipLaunchKernelGGL(zerob_k, dim3(1), dim3(512), 0, stream, bcnt, nbuck);
    hipLaunchKernelGGL(bhist_k, dim3(nblk), dim3(256), 0, stream,
                       eraw, eflag, bcnt, E, N, nbuck, cpb);
    hipLaunchKernelGGL(bscan_k, dim3(1), dim3(512), 0, stream, bcnt, bbase, bcur, nbuck);
    hipLaunchKernelGGL(bin2_k, dim3(nblk), dim3(1024), 0, stream,
                       eraw, eflag, bcur, binned, E, N, nbuck, cpb);
    hipLaunchKernelGGL(scatcnt_k, dim3(nbuck), dim3(256), 0, stream,
                       binned, bbase, row_ptr, dis, colx, N);
  } else {
    hipLaunchKernelGGL(normalize_k, dim3(gE), dim3(256), 0, stream, eraw, eflag, srcN, dstN, E);
    hipLaunchKernelGGL(zero_cnt_k, dim3(gN), dim3(256), 0, stream, cnt, N);
    hipLaunchKernelGGL(count_k, dim3(gE), dim3(256), 0, stream, dstN, cnt, E, N);
    hipLaunchKernelGGL(dis_leg_k, dim3(gN), dim3(256), 0, stream, cnt, dis, N);
    hipLaunchKernelGGL(scan_a_k, dim3(NB), dim3(1024), 0, stream, cnt, row_ptr, bsum, N);
    hipLaunchKernelGGL(scan_b_k, dim3(1), dim3(1024), 0, stream, bsum, NB);
    hipLaunchKernelGGL(scan_c_k, dim3(NB), dim3(1024), 0, stream, row_ptr, bsum, cnt, cursor, N);
    hipLaunchKernelGGL(fill_k, dim3(gE), dim3(256), 0, stream, srcN, dstN, cursor, colx, E, N);
  }

  // collapsed weights
  hipLaunchKernelGGL(wc_k, dim3(FDIM), dim3(64), 0, stream, W2, Wl, Wc);
  hipLaunchKernelGGL(wfull_k, dim3(FDIM), dim3(64), 0, stream, W1, Wc, Wfull);
  hipLaunchKernelGGL(rvec_k, dim3(1), dim3(64), 0, stream, b1, Wc, b2, Wl, bl, b1c, r2);
  hipLaunchKernelGGL(wft_k, dim3(48), dim3(FDIM), 0, stream, Wfull, WfT);

  // Ys = bf16( (X @ Wfull) * dis_row ), dword-packed
  hipLaunchKernelGGL(proj_k, dim3(gP), dim3(256), 0, stream, x, WfT, dis, Ys32, N);
  // Z1s = bf16( (dis_i*(Ys_i + sum) + b1c) * dis_i )
  hipLaunchKernelGGL(agg1_k, dim3(2048), dim3(256), 0, stream,
                     Ys32, row_ptr, colx, dis, b1c, Z1s32, N);
  // out = logsm( dis_i*(Z1s_i + sum) + r2 )
  hipLaunchKernelGGL(agg2_k, dim3(2048), dim3(256), 0, stream,
                     Z1s32, row_ptr, colx, dis, r2, out, N);
}

// Round 10
// 424.625 us; speedup vs baseline: 1.2051x; 1.2051x over previous
//
#include <hip/hip_runtime.h>
#include <hip/hip_bf16.h>

#define FDIM 256
#define FOUT 40
#define RPB 256   // rows per bucket in CSR-build binning
#define ROWB 80   // bytes per bf16 table row (40 * 2)

typedef __attribute__((ext_vector_type(8))) short short8;
typedef __attribute__((ext_vector_type(4))) float floatx4;

__device__ __forceinline__ float bf2f(unsigned short u) {
  unsigned int x = ((unsigned int)u) << 16;
  float f;
  __builtin_memcpy(&f, &x, 4);
  return f;
}
__device__ __forceinline__ unsigned short f2bf(float f) {
  __hip_bfloat16 h = __float2bfloat16(f);
  unsigned short u;
  __builtin_memcpy(&u, &h, 2);
  return u;
}
// packed-bf16 dword helpers
__device__ __forceinline__ float blo(unsigned int v) {
  unsigned int x = v << 16; float f; __builtin_memcpy(&f, &x, 4); return f;
}
__device__ __forceinline__ float bhi(unsigned int v) {
  unsigned int x = v & 0xFFFF0000u; float f; __builtin_memcpy(&f, &x, 4); return f;
}

// ---------------- edge_index layout detection ----------------

__global__ void detect_k(const int* __restrict__ raw, int nwords, int* __restrict__ flag) {
  if (threadIdx.x == 0) *flag = 0;
  __syncthreads();
  int found = 0;
  for (int w = 1 + 2 * threadIdx.x; w < nwords; w += 512)
    if (raw[w] != 0) { found = 1; break; }
  if (found) atomicOr(flag, 1);  // 1 => int32 layout
}

// legacy normalization (fallback path only)
__global__ void normalize_k(const int* __restrict__ raw, const int* __restrict__ flag,
                            int* __restrict__ srcN, int* __restrict__ dstN, int e) {
  int i = blockIdx.x * 256 + threadIdx.x;
  if (i >= e) return;
  if (*flag) {
    srcN[i] = raw[i];
    dstN[i] = raw[e + i];
  } else {
    srcN[i] = raw[2 * i];
    dstN[i] = raw[2 * (e + i)];
  }
}

// ---------------- legacy CSR build (fallback for N > 2^17) ----------------

__global__ void zero_cnt_k(int* cnt, int n) {
  int i = blockIdx.x * 256 + threadIdx.x;
  if (i < n) cnt[i] = 0;
}

__global__ void count_k(const int* __restrict__ dst, int* __restrict__ cnt, int e, int n) {
  int i = blockIdx.x * 256 + threadIdx.x;
  if (i < e) {
    int d = dst[i];
    if (d >= 0 && d < n) atomicAdd(&cnt[d], 1);
  }
}

__global__ void dis_leg_k(const int* __restrict__ cnt, float* __restrict__ dis, int n) {
  int i = blockIdx.x * 256 + threadIdx.x;
  if (i < n) dis[i] = rsqrtf((float)cnt[i] + 1.0f);
}

__global__ void scan_a_k(const int* __restrict__ cnt, int* __restrict__ excl,
                         int* __restrict__ bsum, int n) {
  __shared__ int sh[1024];
  int t = threadIdx.x;
  int gid = blockIdx.x * 1024 + t;
  int v = (gid < n) ? cnt[gid] : 0;
  sh[t] = v;
  __syncthreads();
  for (int off = 1; off < 1024; off <<= 1) {
    int x = (t >= off) ? sh[t - off] : 0;
    __syncthreads();
    sh[t] += x;
    __syncthreads();
  }
  if (gid < n) excl[gid] = sh[t] - v;
  if (t == 1023) bsum[blockIdx.x] = sh[1023];
}

__global__ void scan_b_k(int* __restrict__ bsum, int nb) {
  __shared__ int sh[1024];
  int t = threadIdx.x;
  int v = (t < nb) ? bsum[t] : 0;
  sh[t] = v;
  __syncthreads();
  for (int off = 1; off < 1024; off <<= 1) {
    int x = (t >= off) ? sh[t - off] : 0;
    __syncthreads();
    sh[t] += x;
    __syncthreads();
  }
  if (t < nb) bsum[t] = sh[t] - v;
}

__global__ void scan_c_k(int* __restrict__ row_ptr, const int* __restrict__ bsum,
                         const int* __restrict__ cnt, int* __restrict__ cursor, int n) {
  int gid = blockIdx.x * 1024 + threadIdx.x;
  if (gid < n) {
    int r = row_ptr[gid] + bsum[blockIdx.x];
    row_ptr[gid] = r;
    cursor[gid] = r;
    if (gid == n - 1) row_ptr[n] = r + cnt[gid];
  }
}

__global__ void fill_k(const int* __restrict__ src, const int* __restrict__ dst,
                       int* __restrict__ cursor, int* __restrict__ col, int e, int n) {
  int i = blockIdx.x * 256 + threadIdx.x;
  if (i < e) {
    int d = dst[i];
    if (d >= 0 && d < n) {
      int slot = atomicAdd(&cursor[d], 1);
      int s = src[i];
      s = min(max(s, 0), n - 1);
      col[slot] = s * ROWB;  // byte offset into table
    }
  }
}

// ---------------- bucket-first CSR build (no global per-row atomics) ----------------
// bucket = dst >> 8 (256 rows, <= 512 buckets for N <= 2^17)

__global__ __launch_bounds__(512) void zerob_k(int* __restrict__ bcnt, int nbuck) {
  int t = threadIdx.x;
  if (t < nbuck) bcnt[t] = 0;
}

// pass 0: bucket histogram straight from raw edges; <=512 global atomics per block
__global__ __launch_bounds__(256) void bhist_k(
    const int* __restrict__ raw, const int* __restrict__ flag,
    int* __restrict__ bcnt, int e, int n, int nbuck, int cpb) {
  __shared__ int hist[512];
  int t = threadIdx.x;
  for (int b = t; b < nbuck; b += 256) hist[b] = 0;
  __syncthreads();
  int fl = *flag;
  int start = blockIdx.x * cpb;
  int endc = min(e, start + cpb);
  for (int i = start + t; i < endc; i += 256) {
    int d = fl ? raw[e + i] : raw[2 * (e + i)];
    if (d >= 0 && d < n) atomicAdd(&hist[d >> 8], 1);
  }
  __syncthreads();
  for (int b = t; b < nbuck; b += 256)
    if (hist[b]) atomicAdd(&bcnt[b], hist[b]);
}

// pass 1: scan bucket counts -> bases + cursors (single block)
__global__ __launch_bounds__(512) void bscan_k(
    const int* __restrict__ bcnt, int* __restrict__ bbase,
    int* __restrict__ bcur, int nbuck) {
  __shared__ int sh[512];
  int t = threadIdx.x;
  int v = (t < nbuck) ? bcnt[t] : 0;
  sh[t] = v;
  __syncthreads();
  for (int off = 1; off < 512; off <<= 1) {
    int x = (t >= off) ? sh[t - off] : 0;
    __syncthreads();
    sh[t] += x;
    __syncthreads();
  }
  if (t < nbuck) {
    int ex = sh[t] - v;
    bbase[t] = ex;
    bcur[t] = ex;
  }
  if (t == nbuck - 1) bbase[nbuck] = sh[t];
}

// pass 2: bin edges (from raw) into per-bucket contiguous regions; payload (dst&255, src)
__global__ __launch_bounds__(1024) void bin2_k(
    const int* __restrict__ raw, const int* __restrict__ flag,
    int* __restrict__ bcur, unsigned int* __restrict__ binned,
    int e, int n, int nbuck, int cpb) {
  __shared__ int hist[512];
  __shared__ int base_[512];
  __shared__ int cnt2[512];
  int t = threadIdx.x;
  int fl = *flag;
  int start = blockIdx.x * cpb;
  int endc = min(e, start + cpb);
  for (int b = t; b < nbuck; b += 1024) { hist[b] = 0; cnt2[b] = 0; }
  __syncthreads();
  for (int i = start + t; i < endc; i += 1024) {
    int d = fl ? raw[e + i] : raw[2 * (e + i)];
    if (d >= 0 && d < n) atomicAdd(&hist[d >> 8], 1);
  }
  __syncthreads();
  for (int b = t; b < nbuck; b += 1024) {
    int h = hist[b];
    base_[b] = h ? atomicAdd(&bcur[b], h) : 0;
  }
  __syncthreads();
  for (int i = start + t; i < endc; i += 1024) {
    int d = fl ? raw[e + i] : raw[2 * (e + i)];
    if (d >= 0 && d < n) {
      int s = fl ? raw[i] : raw[2 * i];
      s = min(max(s, 0), n - 1);
      int bk = d >> 8;
      int pos = base_[bk] + atomicAdd(&cnt2[bk], 1);
      binned[pos] = (((unsigned int)(d & 255)) << 17) | (unsigned int)s;
    }
  }
}

// pass 3: per-bucket row count + dis + row_ptr (LDS scan) + scatter to col (byte offsets)
__global__ __launch_bounds__(256) void scatcnt_k(
    const unsigned int* __restrict__ binned, const int* __restrict__ bbase,
    int* __restrict__ row_ptr, float* __restrict__ dis,
    int* __restrict__ col, int n) {
  __shared__ int cnt[RPB];
  __shared__ int sc[RPB];
  __shared__ int cur[RPB];
  int b = blockIdx.x;
  int r0 = b * RPB;
  int r1 = min(n, r0 + RPB);
  int nr = r1 - r0;
  int t = threadIdx.x;
  cnt[t] = 0;
  __syncthreads();
  int e0 = bbase[b], e1 = bbase[b + 1];
  for (int i = e0 + t; i < e1; i += 256)
    atomicAdd(&cnt[binned[i] >> 17], 1);
  __syncthreads();
  int v = cnt[t];
  if (t < nr) dis[r0 + t] = rsqrtf((float)v + 1.0f);
  sc[t] = v;
  __syncthreads();
  for (int off = 1; off < 256; off <<= 1) {
    int x = (t >= off) ? sc[t - off] : 0;
    __syncthreads();
    sc[t] += x;
    __syncthreads();
  }
  int base = e0 + sc[t] - v;  // exclusive
  cur[t] = base;
  if (t < nr) row_ptr[r0 + t] = base;
  if (t == 0 && r1 == n) row_ptr[n] = e1;
  __syncthreads();
  for (int i = e0 + t; i < e1; i += 256) {
    unsigned int p = binned[i];
    int dlow = (int)(p >> 17);
    int slot = atomicAdd(&cur[dlow], 1);
    col[slot] = (int)(p & 0x1FFFF) * ROWB;  // byte offset
  }
}

// ---------------- weight precomputation (linear collapse) ----------------

__global__ __launch_bounds__(64) void wc_k(const float* __restrict__ W2,
                                           const float* __restrict__ Wlin,
                                           float* __restrict__ Wc) {
  __shared__ float row[FDIM];
  int k = blockIdx.x, t = threadIdx.x;
  for (int j = t; j < FDIM; j += 64) row[j] = W2[(size_t)k * FDIM + j];
  __syncthreads();
  if (t < FOUT) {
    float acc = 0.f;
    for (int j = 0; j < FDIM; ++j) acc += row[j] * Wlin[(size_t)j * FOUT + t];
    Wc[(size_t)k * FOUT + t] = acc;
  }
}

__global__ __launch_bounds__(64) void wfull_k(const float* __restrict__ W1,
                                              const float* __restrict__ Wc,
                                              float* __restrict__ Wfull) {
  __shared__ float row[FDIM];
  int k = blockIdx.x, t = threadIdx.x;
  for (int j = t; j < FDIM; j += 64) row[j] = W1[(size_t)k * FDIM + j];
  __syncthreads();
  if (t < FOUT) {
    float acc = 0.f;
    for (int j = 0; j < FDIM; ++j) acc += row[j] * Wc[(size_t)j * FOUT + t];
    Wfull[(size_t)k * FOUT + t] = acc;
  }
}

__global__ __launch_bounds__(64) void rvec_k(const float* __restrict__ b1,
                                             const float* __restrict__ Wc,
                                             const float* __restrict__ b2,
                                             const float* __restrict__ Wlin,
                                             const float* __restrict__ blin,
                                             float* __restrict__ b1c,
                                             float* __restrict__ r2) {
  int t = threadIdx.x;
  if (t < FOUT) {
    float a = 0.f, b = blin[t];
    for (int j = 0; j < FDIM; ++j) {
      a += b1[j] * Wc[(size_t)j * FOUT + t];
      b += b2[j] * Wlin[(size_t)j * FOUT + t];
    }
    b1c[t] = a;
    r2[t] = b;
  }
}

// WfT: bf16 B^T for MFMA, 48 rows (40 real + 8 zero-pad) x 256
__global__ void wft_k(const float* __restrict__ Wfull, unsigned short* __restrict__ WfT) {
  int o = blockIdx.x, k = threadIdx.x;
  WfT[(size_t)o * FDIM + k] = (o < FOUT) ? f2bf(Wfull[(size_t)k * FOUT + o]) : (unsigned short)0;
}

// ---------------- proj: Ys[N][40] = bf16( (X @ Wfull) * dis_row ), dword-packed out ----------------

__global__ __launch_bounds__(256) void proj_k(
    const float* __restrict__ X, const unsigned short* __restrict__ WfT,
    const float* __restrict__ dis, unsigned int* __restrict__ Ys32, int M) {
  __shared__ __align__(16) unsigned short Asm[64 * 40];   // staging + epilogue repack
  __shared__ __align__(16) unsigned short Bsm[48 * 264];
  int t = threadIdx.x;
  int block_m = blockIdx.x * 64;
  int lane = t & 63, wave = t >> 6;
  int q = lane >> 4, rcol = lane & 15;
  for (int idx = t; idx < 48 * 256; idx += 256) {
    int o = idx >> 8, k = idx & 255;
    Bsm[o * 264 + k] = WfT[(size_t)o * FDIM + k];
  }
  floatx4 acc[3] = {};
  int arow = t >> 2, cc = (t & 3) * 8;
  int gm = block_m + arow;
  for (int kk = 0; kk < FDIM; kk += 32) {
    __syncthreads();  // also protects Bsm staging on first iteration
    {
      float4 v0 = {0, 0, 0, 0}, v1 = {0, 0, 0, 0};
      if (gm < M) {
        v0 = *(const float4*)(X + (size_t)gm * FDIM + kk + cc);
        v1 = *(const float4*)(X + (size_t)gm * FDIM + kk + cc + 4);
      }
      short8 pk;
      pk[0] = (short)f2bf(v0.x); pk[1] = (short)f2bf(v0.y);
      pk[2] = (short)f2bf(v0.z); pk[3] = (short)f2bf(v0.w);
      pk[4] = (short)f2bf(v1.x); pk[5] = (short)f2bf(v1.y);
      pk[6] = (short)f2bf(v1.z); pk[7] = (short)f2bf(v1.w);
      *(short8*)(Asm + arow * 40 + cc) = pk;
    }
    __syncthreads();
    short8 af = *(const short8*)(Asm + (wave * 16 + rcol) * 40 + q * 8);
    short8 b0 = *(const short8*)(Bsm + (rcol)*264 + kk + q * 8);
    short8 b1f = *(const short8*)(Bsm + (16 + rcol) * 264 + kk + q * 8);
    short8 b2f = *(const short8*)(Bsm + (32 + rcol) * 264 + kk + q * 8);
    acc[0] = __builtin_amdgcn_mfma_f32_16x16x32_bf16(af, b0, acc[0], 0, 0, 0);
    acc[1] = __builtin_amdgcn_mfma_f32_16x16x32_bf16(af, b1f, acc[1], 0, 0, 0);
    acc[2] = __builtin_amdgcn_mfma_f32_16x16x32_bf16(af, b2f, acc[2], 0, 0, 0);
  }
  // epilogue: scale + bf16 into LDS rows, then coalesced dword copy-out
  __syncthreads();
#pragma unroll
  for (int rr = 0; rr < 4; ++rr) {
    int ml = wave * 16 + q * 4 + rr;
    int m = block_m + ml;
    float sc = (m < M) ? dis[m] : 0.f;
    unsigned short* lrow = Asm + ml * 40;
    lrow[rcol] = f2bf(acc[0][rr] * sc);
    lrow[16 + rcol] = f2bf(acc[1][rr] * sc);
    if (rcol < 8) lrow[32 + rcol] = f2bf(acc[2][rr] * sc);
  }
  __syncthreads();
  const unsigned int* A32 = (const unsigned int*)Asm;
  for (int idx = t; idx < 64 * 20; idx += 256) {
    int r = idx / 20, c = idx - r * 20;
    int m = block_m + r;
    if (m < M) Ys32[(size_t)m * 20 + c] = A32[idx];
  }
}

// ---------------- agg kernels: 6 edges/step, 10 lanes/edge, dwordx2 loads ----------
// lane -> group e = lane/10 (6 edge slots), fp2 = lane%10 (dword pair = 4 feats).
// col[] holds PRE-SCALED byte offsets (src*80). Per step: one ds_bpermute
// broadcasts each group's edge offset; each lane does ONE 8B load (4 bf16).
// Cross-group reduce: 3 shfl per accumulator. 10 requests/edge, ~2.5 VALU/edge.
// (Round-7 structure: proven optimum; r8/r9 full-row-issue variants regressed.)

__global__ __launch_bounds__(256) void agg1_k(
    const unsigned int* __restrict__ T32, const int* __restrict__ row_ptr,
    const int* __restrict__ col, const float* __restrict__ dis,
    const float* __restrict__ b1c, unsigned int* __restrict__ O32, int n) {
  int wave = threadIdx.x >> 6, lane = threadIdx.x & 63;
  int wid = blockIdx.x * 4 + wave;
  int nw = gridDim.x * 4;
  int e = lane / 10;
  int fp2 = lane - e * 10;
  if (e > 5) { e = 5; fp2 = 0; }  // lanes 60-63 duplicate group 5 lane 0
  int e4 = e * 4;
  bool g0 = (e == 0);
  float4 bv = *(const float4*)(b1c + 4 * fp2);
  const char* Tb = (const char*)T32 + fp2 * 8;
  for (int i = wid; i < n; i += nw) {
    uint2 sv = *(const uint2*)(Tb + (size_t)i * ROWB);
    float a0 = g0 ? blo(sv.x) : 0.f;
    float a1 = g0 ? bhi(sv.x) : 0.f;
    float a2 = g0 ? blo(sv.y) : 0.f;
    float a3 = g0 ? bhi(sv.y) : 0.f;
    int beg = row_ptr[i], end = row_ptr[i + 1];
    for (int j0 = beg; j0 < end; j0 += 64) {
      int jj = j0 + lane;
      int cs = (jj < end) ? col[jj] : 0;  // byte offsets
      int cc = min(64, end - j0);
      int k = 0;
      for (; k + 24 <= cc; k += 24) {
        int off[4];
#pragma unroll
        for (int u = 0; u < 4; ++u)
          off[u] = __builtin_amdgcn_ds_bpermute((k + 6 * u) * 4 + e4, cs);
        uint2 g[4];
#pragma unroll
        for (int u = 0; u < 4; ++u)
          g[u] = *(const uint2*)(Tb + (unsigned int)off[u]);
#pragma unroll
        for (int u = 0; u < 4; ++u) {
          a0 += blo(g[u].x); a1 += bhi(g[u].x);
          a2 += blo(g[u].y); a3 += bhi(g[u].y);
        }
      }
      for (; k < cc; k += 6) {
        int off = __builtin_amdgcn_ds_bpermute(k * 4 + e4, cs);
        float wgt = (k + e < cc) ? 1.f : 0.f;
        uint2 g = *(const uint2*)(Tb + (unsigned int)off);
        a0 = fmaf(wgt, blo(g.x), a0);
        a1 = fmaf(wgt, bhi(g.x), a1);
        a2 = fmaf(wgt, blo(g.y), a2);
        a3 = fmaf(wgt, bhi(g.y), a3);
      }
    }
    // reduce across 6 groups (stride 10)
    a0 += __shfl(a0, lane + 30); a1 += __shfl(a1, lane + 30);
    a2 += __shfl(a2, lane + 30); a3 += __shfl(a3, lane + 30);
    a0 += __shfl(a0, lane + 10) + __shfl(a0, lane + 20);
    a1 += __shfl(a1, lane + 10) + __shfl(a1, lane + 20);
    a2 += __shfl(a2, lane + 10) + __shfl(a2, lane + 20);
    a3 += __shfl(a3, lane + 10) + __shfl(a3, lane + 20);
    if (g0) {
      float di = dis[i];
      uint2 p;
      p.x = (unsigned int)f2bf((di * a0 + bv.x) * di) |
            ((unsigned int)f2bf((di * a1 + bv.y) * di) << 16);
      p.y = (unsigned int)f2bf((di * a2 + bv.z) * di) |
            ((unsigned int)f2bf((di * a3 + bv.w) * di) << 16);
      *(uint2*)((char*)O32 + (size_t)i * ROWB + fp2 * 8) = p;
    }
  }
}

__global__ __launch_bounds__(256) void agg2_k(
    const unsigned int* __restrict__ T32, const int* __restrict__ row_ptr,
    const int* __restrict__ col, const float* __restrict__ dis,
    const float* __restrict__ r2, float* __restrict__ out, int n) {
  int wave = threadIdx.x >> 6, lane = threadIdx.x & 63;
  int wid = blockIdx.x * 4 + wave;
  int nw = gridDim.x * 4;
  int e = lane / 10;
  int fp2 = lane - e * 10;
  if (e > 5) { e = 5; fp2 = 0; }
  int e4 = e * 4;
  bool g0 = (e == 0);
  float4 rv = *(const float4*)(r2 + 4 * fp2);
  const char* Tb = (const char*)T32 + fp2 * 8;
  for (int i = wid; i < n; i += nw) {
    uint2 sv = *(const uint2*)(Tb + (size_t)i * ROWB);
    float a0 = g0 ? blo(sv.x) : 0.f;
    float a1 = g0 ? bhi(sv.x) : 0.f;
    float a2 = g0 ? blo(sv.y) : 0.f;
    float a3 = g0 ? bhi(sv.y) : 0.f;
    int beg = row_ptr[i], end = row_ptr[i + 1];
    for (int j0 = beg; j0 < end; j0 += 64) {
      int jj = j0 + lane;
      int cs = (jj < end) ? col[jj] : 0;
      int cc = min(64, end - j0);
      int k = 0;
      for (; k + 24 <= cc; k += 24) {
        int off[4];
#pragma unroll
        for (int u = 0; u < 4; ++u)
          off[u] = __builtin_amdgcn_ds_bpermute((k + 6 * u) * 4 + e4, cs);
        uint2 g[4];
#pragma unroll
        for (int u = 0; u < 4; ++u)
          g[u] = *(const uint2*)(Tb + (unsigned int)off[u]);
#pragma unroll
        for (int u = 0; u < 4; ++u) {
          a0 += blo(g[u].x); a1 += bhi(g[u].x);
          a2 += blo(g[u].y); a3 += bhi(g[u].y);
        }
      }
      for (; k < cc; k += 6) {
        int off = __builtin_amdgcn_ds_bpermute(k * 4 + e4, cs);
        float wgt = (k + e < cc) ? 1.f : 0.f;
        uint2 g = *(const uint2*)(Tb + (unsigned int)off);
        a0 = fmaf(wgt, blo(g.x), a0);
        a1 = fmaf(wgt, bhi(g.x), a1);
        a2 = fmaf(wgt, blo(g.y), a2);
        a3 = fmaf(wgt, bhi(g.y), a3);
      }
    }
    a0 += __shfl(a0, lane + 30); a1 += __shfl(a1, lane + 30);
    a2 += __shfl(a2, lane + 30); a3 += __shfl(a3, lane + 30);
    a0 += __shfl(a0, lane + 10) + __shfl(a0, lane + 20);
    a1 += __shfl(a1, lane + 10) + __shfl(a1, lane + 20);
    a2 += __shfl(a2, lane + 10) + __shfl(a2, lane + 20);
    a3 += __shfl(a3, lane + 10) + __shfl(a3, lane + 20);
    float di = dis[i];
    float v0 = g0 ? (di * a0 + rv.x) : -3.4e38f;
    float v1 = g0 ? (di * a1 + rv.y) : -3.4e38f;
    float v2 = g0 ? (di * a2 + rv.z) : -3.4e38f;
    float v3 = g0 ? (di * a3 + rv.w) : -3.4e38f;
    float m = fmaxf(fmaxf(v0, v1), fmaxf(v2, v3));
#pragma unroll
    for (int off = 32; off; off >>= 1) m = fmaxf(m, __shfl_xor(m, off));
    float s = g0 ? (__expf(v0 - m) + __expf(v1 - m) + __expf(v2 - m) + __expf(v3 - m)) : 0.f;
#pragma unroll
    for (int off = 32; off; off >>= 1) s += __shfl_xor(s, off);
    float lg = m + __logf(s);
    if (g0) {
      float4 o = {v0 - lg, v1 - lg, v2 - lg, v3 - lg};
      *(float4*)(out + (size_t)i * FOUT + 4 * fp2) = o;
    }
  }
}

// ---------------- launch ----------------

extern "C" void kernel_launch(void* const* d_in, const int* in_sizes, int n_in,
                              void* d_out, int out_size, void* d_ws, size_t ws_size,
                              hipStream_t stream) {
  const float* x   = (const float*)d_in[0];
  const int* eraw  = (const int*)d_in[1];
  const float* W1  = (const float*)d_in[2];
  const float* b1  = (const float*)d_in[3];
  const float* W2  = (const float*)d_in[4];
  const float* b2  = (const float*)d_in[5];
  const float* Wl  = (const float*)d_in[6];
  const float* bl  = (const float*)d_in[7];
  float* out = (float*)d_out;

  const int N = in_sizes[0] / FDIM;
  const int E = in_sizes[1] / 2;

  char* w = (char*)d_ws;
  size_t off = 0;
  auto take = [&](size_t bytes) {
    void* p = w + off;
    off = (off + bytes + 255) & ~(size_t)255;
    return p;
  };
  int* cnt     = (int*)take((size_t)N * 4);   // legacy path only
  int* cursor  = (int*)take((size_t)N * 4);   // legacy path only
  int* row_ptr = (int*)take((size_t)(N + 1) * 4);
  float* dis   = (float*)take((size_t)N * 4);
  int* bsum    = (int*)take(4096);
  int* eflag   = (int*)take(256);
  int* bcnt    = (int*)take(512 * 4);
  int* bbase   = (int*)take(513 * 4);
  int* bcur    = (int*)take(512 * 4);
  float* Wc    = (float*)take((size_t)FDIM * FOUT * 4);
  float* Wfull = (float*)take((size_t)FDIM * FOUT * 4);
  unsigned short* WfT = (unsigned short*)take((size_t)48 * FDIM * 2);
  float* b1c   = (float*)take(256);
  float* r2    = (float*)take(256);
  int* colx    = (int*)take((size_t)E * 4);

  size_t pairBytes = (size_t)2 * E * 4;
  size_t tabBytes  = (size_t)N * FOUT * 2;  // bf16 tables (20 dwords/row)
  size_t rABytes = pairBytes > tabBytes ? pairBytes : tabBytes;
  char* regionA = (char*)take(rABytes);
  int* srcN = (int*)regionA;
  int* dstN = srcN + E;
  unsigned int* Ys32 = (unsigned int*)regionA;
  size_t binBytes = (size_t)E * 4;
  size_t rBBytes = binBytes > tabBytes ? binBytes : tabBytes;
  char* regionB = (char*)take(rBBytes);
  unsigned int* binned = (unsigned int*)regionB;
  unsigned int* Z1s32 = (unsigned int*)regionB;
  (void)n_in; (void)out_size; (void)ws_size;

  int gE = (E + 255) / 256;
  int gN = (N + 255) / 256;
  int NB = (N + 1023) / 1024;
  int gP = (N + 63) / 64;
  int nbuck = (N + RPB - 1) / RPB;
  bool bucketed = (N <= (1 << 17));

  int probe_words = 65536 < 2 * E ? 65536 : 2 * E;
  hipLaunchKernelGGL(detect_k, dim3(1), dim3(256), 0, stream, eraw, probe_words, eflag);

  if (bucketed) {
    int nblk = 256;
    int cpb = (E + nblk - 1) / nblk;
    hipLaunchKernelGGL(zerob_k, dim3(1), dim3(512), 0, stream, bcnt, nbuck);
    hipLaunchKernelGGL(bhist_k, dim3(nblk), dim3(256), 0, stream,
                       eraw, eflag, bcnt, E, N, nbuck, cpb);
    hipLaunchKernelGGL(bscan_k, dim3(1), dim3(512), 0, stream, bcnt, bbase, bcur, nbuck);
    hipLaunchKernelGGL(bin2_k, dim3(nblk), dim3(1024), 0, stream,
                       eraw, eflag, bcur, binned, E, N, nbuck, cpb);
    hipLaunchKernelGGL(scatcnt_k, dim3(nbuck), dim3(256), 0, stream,
                       binned, bbase, row_ptr, dis, colx, N);
  } else {
    hipLaunchKernelGGL(normalize_k, dim3(gE), dim3(256), 0, stream, eraw, eflag, srcN, dstN, E);
    hipLaunchKernelGGL(zero_cnt_k, dim3(gN), dim3(256), 0, stream, cnt, N);
    hipLaunchKernelGGL(count_k, dim3(gE), dim3(256), 0, stream, dstN, cnt, E, N);
    hipLaunchKernelGGL(dis_leg_k, dim3(gN), dim3(256), 0, stream, cnt, dis, N);
    hipLaunchKernelGGL(scan_a_k, dim3(NB), dim3(1024), 0, stream, cnt, row_ptr, bsum, N);
    hipLaunchKernelGGL(scan_b_k, dim3(1), dim3(1024), 0, stream, bsum, NB);
    hipLaunchKernelGGL(scan_c_k, dim3(NB), dim3(1024), 0, stream, row_ptr, bsum, cnt, cursor, N);
    hipLaunchKernelGGL(fill_k, dim3(gE), dim3(256), 0, stream, srcN, dstN, cursor, colx, E, N);
  }

  // collapsed weights
  hipLaunchKernelGGL(wc_k, dim3(FDIM), dim3(64), 0, stream, W2, Wl, Wc);
  hipLaunchKernelGGL(wfull_k, dim3(FDIM), dim3(64), 0, stream, W1, Wc, Wfull);
  hipLaunchKernelGGL(rvec_k, dim3(1), dim3(64), 0, stream, b1, Wc, b2, Wl, bl, b1c, r2);
  hipLaunchKernelGGL(wft_k, dim3(48), dim3(FDIM), 0, stream, Wfull, WfT);

  // Ys = bf16( (X @ Wfull) * dis_row ), dword-packed
  hipLaunchKernelGGL(proj_k, dim3(gP), dim3(256), 0, stream, x, WfT, dis, Ys32, N);
  // Z1s = bf16( (dis_i*(Ys_i + sum) + b1c) * dis_i )
  hipLaunchKernelGGL(agg1_k, dim3(2048), dim3(256), 0, stream,
                     Ys32, row_ptr, colx, dis, b1c, Z1s32, N);
  // out = logsm( dis_i*(Z1s_i + sum) + r2 )
  hipLaunchKernelGGL(agg2_k, dim3(2048), dim3(256), 0, stream,
                     Z1s32, row_ptr, colx, dis, r2, out, N);
}